// Round 10
// baseline (58.825 us; speedup 1.0000x reference)
//
#include <hip/hip_runtime.h>

#define KC 32
#define CH 16
#define NB 8
#define NPI (512*512)

// segsum decomposition: 2048 blocks of 256 threads (8 blocks/CU)
#define SBPI 256              // blocks per image
#define SPPB (NPI/SBPI)       // 1024 px per block
#define SPW  (SPPB/4)         // 256 px per wave
#define SCH  (SPW/64)         // 4 chunks of 64 px
#define PAD  69               // LDS px-stride: (5p+8g)%32 all-distinct -> conflict-free b128

// pull decomposition: 2048 blocks of 256 threads
#define PBPI 256
#define PPPB (NPI/PBPI)       // 1024
#define PIT  (PPPB/256)       // 4

// ws layout (floats); every cell written before read each call -> no pre-zero
#define WS_PART 0                          // [2048][544] per-block segsum partials ([k][c|cnt])
#define WS_SUMS (WS_PART + NB*SBPI*544)    // [8][544] per-image reduced sums
#define WS_CEN (WS_SUMS + NB*544)          // [8][16][32] centroids [c][k]
#define WS_PR  (WS_CEN + NB*CH*KC)         // [8] push + 1e-4*reg
#define WS_PLP (WS_PR + NB)                // [2048] pull partials

typedef float f32x4 __attribute__((ext_vector_type(4)));
typedef short short8 __attribute__((ext_vector_type(8)));

__device__ __forceinline__ unsigned packbf(float lo, float hi) {
  unsigned r;
  asm("v_cvt_pk_bf16_f32 %0, %1, %2" : "=v"(r) : "v"(lo), "v"(hi));
  return r;   // low16 = bf16(lo), high16 = bf16(hi), RNE
}

// sums[k][c] via onehot^T * emb with TWO 16x16x32 bf16 MFMAs per 32 px
// (labels 0-15 and 16-31); counts in registers (CSE'd with the onehot compares).
// Per-wave private LDS staging (in-order DS per wave => no barriers in hot loop).
__global__ __launch_bounds__(256) void segsum_kernel(
    const float4* __restrict__ embv, const int* __restrict__ lab,
    float* __restrict__ ws) {
  __shared__ unsigned smem[4][8][PAD];  // [wave][ch-pair][px(stride PAD)] bf16x2
  __shared__ int      slab[4][64];
  __shared__ float    sred[4][KC * 17];

  const int t = threadIdx.x, w = t >> 6, l = t & 63;
  const int b = blockIdx.x / SBPI, blk = blockIdx.x % SBPI;
  const size_t base = (size_t)b * NPI + (size_t)blk * SPPB + (size_t)w * SPW;
  const int ch = l & 15;       // B col (channel) / A row (label, +16 for acc1)
  const int g  = l >> 4;       // k-slice group: px slice g*8..g*8+8 within 32-px step
  const int ch16 = ch + 16;

  f32x4 acc0, acc1;
  #pragma unroll
  for (int i = 0; i < 4; ++i) { acc0[i] = 0.f; acc1[i] = 0.f; }
  int cnt0 = 0, cnt1 = 0;

  float4 c0, c1, c2, c3; int cl;
  {
    const float4* ep = embv + (base + l) * 4;
    c0 = ep[0]; c1 = ep[1]; c2 = ep[2]; c3 = ep[3];
    cl = lab[base + l];
  }

  for (int chk = 0; chk < SCH; ++chk) {
    smem[w][0][l] = packbf(c0.x, c0.y);
    smem[w][1][l] = packbf(c0.z, c0.w);
    smem[w][2][l] = packbf(c1.x, c1.y);
    smem[w][3][l] = packbf(c1.z, c1.w);
    smem[w][4][l] = packbf(c2.x, c2.y);
    smem[w][5][l] = packbf(c2.z, c2.w);
    smem[w][6][l] = packbf(c3.x, c3.y);
    smem[w][7][l] = packbf(c3.z, c3.w);
    slab[w][l] = cl;

    if (chk + 1 < SCH) {                // prefetch next chunk under the MFMA steps
      const size_t p = base + (size_t)(chk + 1) * 64 + l;
      const float4* ep = embv + p * 4;
      c0 = ep[0]; c1 = ep[1]; c2 = ep[2]; c3 = ep[3];
      cl = lab[p];
    }

    #pragma unroll
    for (int s = 0; s < 2; ++s) {       // 32 px per step
      const int px0 = s * 32 + g * 8;
      const int4 la = *(const int4*)&slab[w][px0];
      const int4 lb = *(const int4*)&slab[w][px0 + 4];
      const short ONE = (short)0x3F80;  // bf16 1.0

      short8 a0, a1;
      a0[0] = (la.x == ch) ? ONE : (short)0; a0[1] = (la.y == ch) ? ONE : (short)0;
      a0[2] = (la.z == ch) ? ONE : (short)0; a0[3] = (la.w == ch) ? ONE : (short)0;
      a0[4] = (lb.x == ch) ? ONE : (short)0; a0[5] = (lb.y == ch) ? ONE : (short)0;
      a0[6] = (lb.z == ch) ? ONE : (short)0; a0[7] = (lb.w == ch) ? ONE : (short)0;
      a1[0] = (la.x == ch16) ? ONE : (short)0; a1[1] = (la.y == ch16) ? ONE : (short)0;
      a1[2] = (la.z == ch16) ? ONE : (short)0; a1[3] = (la.w == ch16) ? ONE : (short)0;
      a1[4] = (lb.x == ch16) ? ONE : (short)0; a1[5] = (lb.y == ch16) ? ONE : (short)0;
      a1[6] = (lb.z == ch16) ? ONE : (short)0; a1[7] = (lb.w == ch16) ? ONE : (short)0;
      cnt0 += (la.x == ch) + (la.y == ch) + (la.z == ch) + (la.w == ch)
            + (lb.x == ch) + (lb.y == ch) + (lb.z == ch) + (lb.w == ch);
      cnt1 += (la.x == ch16) + (la.y == ch16) + (la.z == ch16) + (la.w == ch16)
            + (lb.x == ch16) + (lb.y == ch16) + (lb.z == ch16) + (lb.w == ch16);

      const uint4 u0 = *(const uint4*)&smem[w][ch >> 1][px0];
      const uint4 u1 = *(const uint4*)&smem[w][ch >> 1][px0 + 4];
      const unsigned sh = (unsigned)(ch & 1) * 16u;
      short8 bv;
      bv[0] = (short)(u0.x >> sh); bv[1] = (short)(u0.y >> sh);
      bv[2] = (short)(u0.z >> sh); bv[3] = (short)(u0.w >> sh);
      bv[4] = (short)(u1.x >> sh); bv[5] = (short)(u1.y >> sh);
      bv[6] = (short)(u1.z >> sh); bv[7] = (short)(u1.w >> sh);

      acc0 = __builtin_amdgcn_mfma_f32_16x16x32_bf16(a0, bv, acc0, 0, 0, 0);
      acc1 = __builtin_amdgcn_mfma_f32_16x16x32_bf16(a1, bv, acc1, 0, 0, 0);
    }
  }

  // D layout (16x16, verified m89/m91): lane holds D[row=(l>>4)*4+r][col=l&15]
  #pragma unroll
  for (int r = 0; r < 4; ++r) {
    sred[w][(g * 4 + r) * 17 + ch]        = acc0[r];
    sred[w][(g * 4 + r + 16) * 17 + ch]   = acc1[r];
  }
  // counts: sum the 4 k-slice groups (lanes l, l^16, l^32, l^48 share ch)
  cnt0 += __shfl_xor(cnt0, 16, 64); cnt0 += __shfl_xor(cnt0, 32, 64);
  cnt1 += __shfl_xor(cnt1, 16, 64); cnt1 += __shfl_xor(cnt1, 32, 64);
  if (l < 16) {
    sred[w][l * 17 + 16]        = (float)cnt0;
    sred[w][(l + 16) * 17 + 16] = (float)cnt1;
  }
  __syncthreads();
  for (int i = t; i < KC * 17; i += 256) {
    const float v = sred[0][i] + sred[1][i] + sred[2][i] + sred[3][i];
    ws[WS_PART + (size_t)blockIdx.x * 544 + i] = v;
  }
}

// Parallel partial-reduce: 136 blocks = 8 images x 17 cell-chunks of 32.
__global__ __launch_bounds__(256) void mid_reduce_kernel(float* __restrict__ ws) {
  __shared__ float part[8][33];     // [pslice][cell], padded
  const int g = blockIdx.x, t = threadIdx.x;
  const int img = g / 17, c0 = (g % 17) * 32;
  const int cidx = t & 31, ps = t >> 5;

  const float* base = ws + WS_PART + (size_t)(img * SBPI) * 544 + c0 + cidx;
  float s = 0.f;
  #pragma unroll 8
  for (int q = 0; q < SBPI / 8; ++q)
    s += base[(size_t)(ps + 8 * q) * 544];
  part[ps][cidx] = s;
  __syncthreads();
  if (t < 32) {
    float v = 0.f;
    #pragma unroll
    for (int i = 0; i < 8; ++i) v += part[i][t];
    ws[WS_SUMS + img * 544 + c0 + t] = v;
  }
}

// Centroids + push + reg from the reduced sums. One block per image.
__global__ __launch_bounds__(512) void centroid_push_kernel(float* __restrict__ ws) {
  __shared__ float sums_s[KC * 17];  // [k][c|cnt]
  __shared__ float cent[CH * KC];    // [c][k]
  __shared__ float validf[KC];
  __shared__ float red[8];
  const int b = blockIdx.x, t = threadIdx.x;

  for (int i = t; i < KC * 17; i += 512) sums_s[i] = ws[WS_SUMS + b * 544 + i];
  __syncthreads();

  if (t < KC) validf[t] = (sums_s[t * 17 + 16] > 0.f) ? 1.f : 0.f;

  const int k = t & 31, c = t >> 5;   // t in [0,512) covers all (k,c)
  const float cnt = sums_s[k * 17 + 16];
  const float ce  = (cnt > 0.f) ? sums_s[k * 17 + c] / cnt : 0.f;
  cent[c * KC + k] = ce;
  ws[WS_CEN + (size_t)b * CH * KC + c * KC + k] = ce;
  const float regacc = ce * ce;
  __syncthreads();

  float pushacc = 0.f;
  for (int p = t; p < KC * KC; p += 512) {
    const int i = p >> 5, j = p & 31;
    if (i < j && validf[i] > 0.f && validf[j] > 0.f) {
      float pd = 0.f;
      #pragma unroll
      for (int cc = 0; cc < CH; ++cc)
        pd += fabsf(cent[cc * KC + i] - cent[cc * KC + j]);
      const float hi = 0.25f - pd;
      if (hi > 0.f) pushacc += hi * hi;
    }
  }

  float v = pushacc;
  #pragma unroll
  for (int off = 32; off; off >>= 1) v += __shfl_down(v, off, 64);
  if ((t & 63) == 0) red[t >> 6] = v;
  __syncthreads();
  float pushsum = 0.f;
  if (t == 0) { for (int i = 0; i < 8; ++i) pushsum += red[i]; }
  __syncthreads();

  v = regacc;
  #pragma unroll
  for (int off = 32; off; off >>= 1) v += __shfl_down(v, off, 64);
  if ((t & 63) == 0) red[t >> 6] = v;
  __syncthreads();

  if (t == 0) {
    float regsum = 0.f;
    for (int i = 0; i < 8; ++i) regsum += red[i];
    float nv = 0.f;
    for (int i = 0; i < KC; ++i) nv += validf[i];
    const float ncomp = nv * (nv - 1.f) * 0.5f;
    const float push  = (nv >= 2.f) ? pushsum / fmaxf(ncomp, 1.f) : 0.f;
    const float reg   = regsum / fmaxf(nv * (float)CH, 1.f);
    ws[WS_PR + b] = push + 1e-4f * reg;
  }
}

__global__ __launch_bounds__(256) void pull_kernel(
    const float4* __restrict__ embv, const int* __restrict__ lab,
    float* __restrict__ ws) {
  __shared__ float cent[CH * KC];   // [c][k]: bank == label -> broadcast/spread, conflict-free
  __shared__ float red[4];
  const int t = threadIdx.x;
  const int b = blockIdx.x / PBPI, blk = blockIdx.x % PBPI;
  for (int i = t; i < CH * KC; i += 256)
    cent[i] = ws[WS_CEN + (size_t)b * CH * KC + i];
  __syncthreads();

  float acc = 0.f;
  const size_t pix0 = (size_t)b * NPI + (size_t)blk * PPPB;
  for (int it = 0; it < PIT; ++it) {
    const size_t p = pix0 + (size_t)it * 256 + t;
    const int L = lab[p];
    const float4 v0 = embv[p * 4 + 0];
    const float4 v1 = embv[p * 4 + 1];
    const float4 v2 = embv[p * 4 + 2];
    const float4 v3 = embv[p * 4 + 3];
    float d = 0.f;
    d += fabsf(v0.x - cent[ 0 * KC + L]);
    d += fabsf(v0.y - cent[ 1 * KC + L]);
    d += fabsf(v0.z - cent[ 2 * KC + L]);
    d += fabsf(v0.w - cent[ 3 * KC + L]);
    d += fabsf(v1.x - cent[ 4 * KC + L]);
    d += fabsf(v1.y - cent[ 5 * KC + L]);
    d += fabsf(v1.z - cent[ 6 * KC + L]);
    d += fabsf(v1.w - cent[ 7 * KC + L]);
    d += fabsf(v2.x - cent[ 8 * KC + L]);
    d += fabsf(v2.y - cent[ 9 * KC + L]);
    d += fabsf(v2.z - cent[10 * KC + L]);
    d += fabsf(v2.w - cent[11 * KC + L]);
    d += fabsf(v3.x - cent[12 * KC + L]);
    d += fabsf(v3.y - cent[13 * KC + L]);
    d += fabsf(v3.z - cent[14 * KC + L]);
    d += fabsf(v3.w - cent[15 * KC + L]);
    acc += d * d;
  }
  #pragma unroll
  for (int off = 32; off; off >>= 1) acc += __shfl_down(acc, off, 64);
  if ((t & 63) == 0) red[t >> 6] = acc;
  __syncthreads();
  if (t == 0) ws[WS_PLP + blockIdx.x] = red[0] + red[1] + red[2] + red[3];
}

__global__ void final_kernel(const float* __restrict__ ws, float* __restrict__ out) {
  __shared__ float simg[NB];
  const int t = threadIdx.x;            // 256 threads
  const int img = t >> 5, j = t & 31;   // 32 threads per image
  float v = 0.f;
  #pragma unroll
  for (int q = 0; q < PBPI / 32; ++q)
    v += ws[WS_PLP + img * PBPI + j + 32 * q];
  #pragma unroll
  for (int off = 16; off; off >>= 1) v += __shfl_down(v, off, 32);
  if (j == 0) simg[img] = v;
  __syncthreads();
  if (t == 0) {
    float s = 0.f;
    for (int b2 = 0; b2 < NB; ++b2)
      s += ws[WS_PR + b2] + simg[b2] * (1.f / (float)NPI);
    out[0] = s * (1.f / (float)NB);
  }
}

extern "C" void kernel_launch(void* const* d_in, const int* in_sizes, int n_in,
                              void* d_out, int out_size, void* d_ws, size_t ws_size,
                              hipStream_t stream) {
  const float4* emb = (const float4*)d_in[0];
  const int*    lab = (const int*)d_in[1];
  float* ws  = (float*)d_ws;
  float* out = (float*)d_out;

  hipLaunchKernelGGL(segsum_kernel, dim3(NB * SBPI), dim3(256), 0, stream, emb, lab, ws);
  hipLaunchKernelGGL(mid_reduce_kernel, dim3(NB * 17), dim3(256), 0, stream, ws);
  hipLaunchKernelGGL(centroid_push_kernel, dim3(NB), dim3(512), 0, stream, ws);
  hipLaunchKernelGGL(pull_kernel, dim3(NB * PBPI), dim3(256), 0, stream, emb, lab, ws);
  hipLaunchKernelGGL(final_kernel, dim3(1), dim3(256), 0, stream, ws, out);
}

// Round 11
// 57.668 us; speedup vs baseline: 1.0201x; 1.0201x over previous
//
#include <hip/hip_runtime.h>

#define KC 32
#define CH 16
#define NB 8
#define NPI (512*512)

// segsum decomposition: 2048 blocks of 256 threads (8 blocks/CU)
#define SBPI 256              // blocks per image
#define SPPB (NPI/SBPI)       // 1024 px per block
#define SPW  (SPPB/4)         // 256 px per wave
#define SCH  (SPW/64)         // 4 chunks of 64 px
#define PAD  69               // LDS px-stride: conflict-free b128 fragment reads

// pull decomposition: 2048 blocks of 256 threads, 4 px/thread, 2-deep pipeline
#define PBPI 256
#define PPPB (NPI/PBPI)       // 1024

// ws layout (floats); every cell written before read each call -> no pre-zero
#define WS_PART 0                          // [2048][544] per-block segsum partials ([k][c|cnt])
#define WS_SUMS (WS_PART + NB*SBPI*544)    // [8][544] per-image reduced sums
#define WS_CEN (WS_SUMS + NB*544)          // [8][16][32] centroids [c][k]
#define WS_PR  (WS_CEN + NB*CH*KC)         // [8] push + 1e-4*reg
#define WS_PLP (WS_PR + NB)                // [2048] pull partials

typedef float f32x4 __attribute__((ext_vector_type(4)));
typedef short short8 __attribute__((ext_vector_type(8)));

__device__ __forceinline__ unsigned packbf(float lo, float hi) {
  unsigned r;
  asm("v_cvt_pk_bf16_f32 %0, %1, %2" : "=v"(r) : "v"(lo), "v"(hi));
  return r;   // low16 = bf16(lo), high16 = bf16(hi), RNE
}

// sums[k][c] via onehot^T * emb with TWO 16x16x32 bf16 MFMAs per 32 px
// (labels 0-15 and 16-31); counts in registers (CSE'd with the onehot compares).
// Per-wave private LDS staging (in-order DS per wave => no barriers in hot loop).
__global__ __launch_bounds__(256) void segsum_kernel(
    const float4* __restrict__ embv, const int* __restrict__ lab,
    float* __restrict__ ws) {
  __shared__ unsigned smem[4][8][PAD];  // [wave][ch-pair][px(stride PAD)] bf16x2
  __shared__ int      slab[4][64];
  __shared__ float    sred[4][KC * 17];

  const int t = threadIdx.x, w = t >> 6, l = t & 63;
  const int b = blockIdx.x / SBPI, blk = blockIdx.x % SBPI;
  const size_t base = (size_t)b * NPI + (size_t)blk * SPPB + (size_t)w * SPW;
  const int ch = l & 15;       // B col (channel) / A row (label, +16 for acc1)
  const int g  = l >> 4;       // k-slice group
  const int ch16 = ch + 16;

  f32x4 acc0, acc1;
  #pragma unroll
  for (int i = 0; i < 4; ++i) { acc0[i] = 0.f; acc1[i] = 0.f; }
  int cnt0 = 0, cnt1 = 0;

  float4 c0, c1, c2, c3; int cl;
  {
    const float4* ep = embv + (base + l) * 4;
    c0 = ep[0]; c1 = ep[1]; c2 = ep[2]; c3 = ep[3];
    cl = lab[base + l];
  }

  for (int chk = 0; chk < SCH; ++chk) {
    smem[w][0][l] = packbf(c0.x, c0.y);
    smem[w][1][l] = packbf(c0.z, c0.w);
    smem[w][2][l] = packbf(c1.x, c1.y);
    smem[w][3][l] = packbf(c1.z, c1.w);
    smem[w][4][l] = packbf(c2.x, c2.y);
    smem[w][5][l] = packbf(c2.z, c2.w);
    smem[w][6][l] = packbf(c3.x, c3.y);
    smem[w][7][l] = packbf(c3.z, c3.w);
    slab[w][l] = cl;

    if (chk + 1 < SCH) {                // prefetch next chunk under the MFMA steps
      const size_t p = base + (size_t)(chk + 1) * 64 + l;
      const float4* ep = embv + p * 4;
      c0 = ep[0]; c1 = ep[1]; c2 = ep[2]; c3 = ep[3];
      cl = lab[p];
    }

    #pragma unroll
    for (int s = 0; s < 2; ++s) {       // 32 px per step
      const int px0 = s * 32 + g * 8;
      const int4 la = *(const int4*)&slab[w][px0];
      const int4 lb = *(const int4*)&slab[w][px0 + 4];
      const short ONE = (short)0x3F80;  // bf16 1.0

      short8 a0, a1;
      a0[0] = (la.x == ch) ? ONE : (short)0; a0[1] = (la.y == ch) ? ONE : (short)0;
      a0[2] = (la.z == ch) ? ONE : (short)0; a0[3] = (la.w == ch) ? ONE : (short)0;
      a0[4] = (lb.x == ch) ? ONE : (short)0; a0[5] = (lb.y == ch) ? ONE : (short)0;
      a0[6] = (lb.z == ch) ? ONE : (short)0; a0[7] = (lb.w == ch) ? ONE : (short)0;
      a1[0] = (la.x == ch16) ? ONE : (short)0; a1[1] = (la.y == ch16) ? ONE : (short)0;
      a1[2] = (la.z == ch16) ? ONE : (short)0; a1[3] = (la.w == ch16) ? ONE : (short)0;
      a1[4] = (lb.x == ch16) ? ONE : (short)0; a1[5] = (lb.y == ch16) ? ONE : (short)0;
      a1[6] = (lb.z == ch16) ? ONE : (short)0; a1[7] = (lb.w == ch16) ? ONE : (short)0;
      cnt0 += (la.x == ch) + (la.y == ch) + (la.z == ch) + (la.w == ch)
            + (lb.x == ch) + (lb.y == ch) + (lb.z == ch) + (lb.w == ch);
      cnt1 += (la.x == ch16) + (la.y == ch16) + (la.z == ch16) + (la.w == ch16)
            + (lb.x == ch16) + (lb.y == ch16) + (lb.z == ch16) + (lb.w == ch16);

      const uint4 u0 = *(const uint4*)&smem[w][ch >> 1][px0];
      const uint4 u1 = *(const uint4*)&smem[w][ch >> 1][px0 + 4];
      const unsigned sh = (unsigned)(ch & 1) * 16u;
      short8 bv;
      bv[0] = (short)(u0.x >> sh); bv[1] = (short)(u0.y >> sh);
      bv[2] = (short)(u0.z >> sh); bv[3] = (short)(u0.w >> sh);
      bv[4] = (short)(u1.x >> sh); bv[5] = (short)(u1.y >> sh);
      bv[6] = (short)(u1.z >> sh); bv[7] = (short)(u1.w >> sh);

      acc0 = __builtin_amdgcn_mfma_f32_16x16x32_bf16(a0, bv, acc0, 0, 0, 0);
      acc1 = __builtin_amdgcn_mfma_f32_16x16x32_bf16(a1, bv, acc1, 0, 0, 0);
    }
  }

  // D layout (16x16, verified m89/m91): lane holds D[row=(l>>4)*4+r][col=l&15]
  #pragma unroll
  for (int r = 0; r < 4; ++r) {
    sred[w][(g * 4 + r) * 17 + ch]        = acc0[r];
    sred[w][(g * 4 + r + 16) * 17 + ch]   = acc1[r];
  }
  cnt0 += __shfl_xor(cnt0, 16, 64); cnt0 += __shfl_xor(cnt0, 32, 64);
  cnt1 += __shfl_xor(cnt1, 16, 64); cnt1 += __shfl_xor(cnt1, 32, 64);
  if (l < 16) {
    sred[w][l * 17 + 16]        = (float)cnt0;
    sred[w][(l + 16) * 17 + 16] = (float)cnt1;
  }
  __syncthreads();
  for (int i = t; i < KC * 17; i += 256) {
    const float v = sred[0][i] + sred[1][i] + sred[2][i] + sred[3][i];
    ws[WS_PART + (size_t)blockIdx.x * 544 + i] = v;
  }
}

// Parallel partial-reduce: 136 blocks = 8 images x 17 cell-chunks of 32.
__global__ __launch_bounds__(256) void mid_reduce_kernel(float* __restrict__ ws) {
  __shared__ float part[8][33];     // [pslice][cell], padded
  const int g = blockIdx.x, t = threadIdx.x;
  const int img = g / 17, c0 = (g % 17) * 32;
  const int cidx = t & 31, ps = t >> 5;

  const float* base = ws + WS_PART + (size_t)(img * SBPI) * 544 + c0 + cidx;
  float s = 0.f;
  #pragma unroll 8
  for (int q = 0; q < SBPI / 8; ++q)
    s += base[(size_t)(ps + 8 * q) * 544];
  part[ps][cidx] = s;
  __syncthreads();
  if (t < 32) {
    float v = 0.f;
    #pragma unroll
    for (int i = 0; i < 8; ++i) v += part[i][t];
    ws[WS_SUMS + img * 544 + c0 + t] = v;
  }
}

// Centroids + push + reg from the reduced sums. One block per image.
__global__ __launch_bounds__(512) void centroid_push_kernel(float* __restrict__ ws) {
  __shared__ float sums_s[KC * 17];  // [k][c|cnt]
  __shared__ float cent[CH * KC];    // [c][k]
  __shared__ float validf[KC];
  __shared__ float red[8];
  const int b = blockIdx.x, t = threadIdx.x;

  for (int i = t; i < KC * 17; i += 512) sums_s[i] = ws[WS_SUMS + b * 544 + i];
  __syncthreads();

  if (t < KC) validf[t] = (sums_s[t * 17 + 16] > 0.f) ? 1.f : 0.f;

  const int k = t & 31, c = t >> 5;   // t in [0,512) covers all (k,c)
  const float cnt = sums_s[k * 17 + 16];
  const float ce  = (cnt > 0.f) ? sums_s[k * 17 + c] / cnt : 0.f;
  cent[c * KC + k] = ce;
  ws[WS_CEN + (size_t)b * CH * KC + c * KC + k] = ce;
  const float regacc = ce * ce;
  __syncthreads();

  float pushacc = 0.f;
  for (int p = t; p < KC * KC; p += 512) {
    const int i = p >> 5, j = p & 31;
    if (i < j && validf[i] > 0.f && validf[j] > 0.f) {
      float pd = 0.f;
      #pragma unroll
      for (int cc = 0; cc < CH; ++cc)
        pd += fabsf(cent[cc * KC + i] - cent[cc * KC + j]);
      const float hi = 0.25f - pd;
      if (hi > 0.f) pushacc += hi * hi;
    }
  }

  float v = pushacc;
  #pragma unroll
  for (int off = 32; off; off >>= 1) v += __shfl_down(v, off, 64);
  if ((t & 63) == 0) red[t >> 6] = v;
  __syncthreads();
  float pushsum = 0.f;
  if (t == 0) { for (int i = 0; i < 8; ++i) pushsum += red[i]; }
  __syncthreads();

  v = regacc;
  #pragma unroll
  for (int off = 32; off; off >>= 1) v += __shfl_down(v, off, 64);
  if ((t & 63) == 0) red[t >> 6] = v;
  __syncthreads();

  if (t == 0) {
    float regsum = 0.f;
    for (int i = 0; i < 8; ++i) regsum += red[i];
    float nv = 0.f;
    for (int i = 0; i < KC; ++i) nv += validf[i];
    const float ncomp = nv * (nv - 1.f) * 0.5f;
    const float push  = (nv >= 2.f) ? pushsum / fmaxf(ncomp, 1.f) : 0.f;
    const float reg   = regsum / fmaxf(nv * (float)CH, 1.f);
    ws[WS_PR + b] = push + 1e-4f * reg;
  }
}

__device__ __forceinline__ float pullPx(const float* __restrict__ cent, int L,
                                        float4 e0, float4 e1, float4 e2, float4 e3) {
  float d = 0.f;
  d += fabsf(e0.x - cent[ 0 * KC + L]); d += fabsf(e0.y - cent[ 1 * KC + L]);
  d += fabsf(e0.z - cent[ 2 * KC + L]); d += fabsf(e0.w - cent[ 3 * KC + L]);
  d += fabsf(e1.x - cent[ 4 * KC + L]); d += fabsf(e1.y - cent[ 5 * KC + L]);
  d += fabsf(e1.z - cent[ 6 * KC + L]); d += fabsf(e1.w - cent[ 7 * KC + L]);
  d += fabsf(e2.x - cent[ 8 * KC + L]); d += fabsf(e2.y - cent[ 9 * KC + L]);
  d += fabsf(e2.z - cent[10 * KC + L]); d += fabsf(e2.w - cent[11 * KC + L]);
  d += fabsf(e3.x - cent[12 * KC + L]); d += fabsf(e3.y - cent[13 * KC + L]);
  d += fabsf(e3.z - cent[14 * KC + L]); d += fabsf(e3.w - cent[15 * KC + L]);
  return d;
}

// pull with 2 pixels in flight per thread (2-deep prefetch, round-6 phaseC structure)
__global__ __launch_bounds__(256) void pull_kernel(
    const float4* __restrict__ embv, const int* __restrict__ lab,
    float* __restrict__ ws) {
  __shared__ float cent[CH * KC];   // [c][k]: bank == label -> broadcast/spread
  __shared__ float red[4];
  const int t = threadIdx.x;
  const int b = blockIdx.x / PBPI, blk = blockIdx.x % PBPI;
  for (int i = t; i < CH * KC; i += 256)
    cent[i] = ws[WS_CEN + (size_t)b * CH * KC + i];
  __syncthreads();

  const size_t base = (size_t)b * NPI + (size_t)blk * PPPB;
  float pacc = 0.f;

  int la, lb_;
  float4 fa0, fa1, fa2, fa3, fb0, fb1, fb2, fb3;
  {
    const float4* ep = embv + (base + t) * 4;
    fa0 = ep[0]; fa1 = ep[1]; fa2 = ep[2]; fa3 = ep[3];
    la = lab[base + t];
  }
  {
    const float4* ep = embv + (base + 256 + t) * 4;
    fb0 = ep[0]; fb1 = ep[1]; fb2 = ep[2]; fb3 = ep[3];
    lb_ = lab[base + 256 + t];
  }

  #pragma unroll
  for (int q = 0; q < 4; q += 2) {
    {
      const float d = pullPx(cent, la, fa0, fa1, fa2, fa3);
      pacc += d * d;
    }
    if (q + 2 < 4) {
      const size_t p = base + (size_t)(q + 2) * 256 + t;
      const float4* ep = embv + p * 4;
      fa0 = ep[0]; fa1 = ep[1]; fa2 = ep[2]; fa3 = ep[3];
      la = lab[p];
    }
    {
      const float d = pullPx(cent, lb_, fb0, fb1, fb2, fb3);
      pacc += d * d;
    }
    if (q + 3 < 4) {
      const size_t p = base + (size_t)(q + 3) * 256 + t;
      const float4* ep = embv + p * 4;
      fb0 = ep[0]; fb1 = ep[1]; fb2 = ep[2]; fb3 = ep[3];
      lb_ = lab[p];
    }
  }

  float v = pacc;
  #pragma unroll
  for (int off = 32; off; off >>= 1) v += __shfl_down(v, off, 64);
  if ((t & 63) == 0) red[t >> 6] = v;
  __syncthreads();
  if (t == 0) ws[WS_PLP + blockIdx.x] = red[0] + red[1] + red[2] + red[3];
}

__global__ void final_kernel(const float* __restrict__ ws, float* __restrict__ out) {
  __shared__ float simg[NB];
  const int t = threadIdx.x;            // 256 threads
  const int img = t >> 5, j = t & 31;   // 32 threads per image
  float v = 0.f;
  #pragma unroll
  for (int q = 0; q < PBPI / 32; ++q)
    v += ws[WS_PLP + img * PBPI + j + 32 * q];
  #pragma unroll
  for (int off = 16; off; off >>= 1) v += __shfl_down(v, off, 32);
  if (j == 0) simg[img] = v;
  __syncthreads();
  if (t == 0) {
    float s = 0.f;
    for (int b2 = 0; b2 < NB; ++b2)
      s += ws[WS_PR + b2] + simg[b2] * (1.f / (float)NPI);
    out[0] = s * (1.f / (float)NB);
  }
}

extern "C" void kernel_launch(void* const* d_in, const int* in_sizes, int n_in,
                              void* d_out, int out_size, void* d_ws, size_t ws_size,
                              hipStream_t stream) {
  const float4* emb = (const float4*)d_in[0];
  const int*    lab = (const int*)d_in[1];
  float* ws  = (float*)d_ws;
  float* out = (float*)d_out;

  hipLaunchKernelGGL(segsum_kernel, dim3(NB * SBPI), dim3(256), 0, stream, emb, lab, ws);
  hipLaunchKernelGGL(mid_reduce_kernel, dim3(NB * 17), dim3(256), 0, stream, ws);
  hipLaunchKernelGGL(centroid_push_kernel, dim3(NB), dim3(512), 0, stream, ws);
  hipLaunchKernelGGL(pull_kernel, dim3(NB * PBPI), dim3(256), 0, stream, emb, lab, ws);
  hipLaunchKernelGGL(final_kernel, dim3(1), dim3(256), 0, stream, ws, out);
}